// Round 15
// baseline (398.560 us; speedup 1.0000x reference)
//
#include <hip/hip_runtime.h>
#include <hip/hip_bf16.h>

#define NN 100000
#define NE 1200000
#define NE4 (NE / 4)                         // 300000
#define CAP 32                               // bucket capacity (P(deg>32) ~ 3e-7/node; spill covers)
#define SPILL_MAX 4096

typedef float floatx2 __attribute__((ext_vector_type(2)));

// ---------------- single-pass CSR-bucket build via device-scope atomics ----------------
// R14 probe: stores to non-owned lines caused 16x write amplification (R3: 85MB for
// 4.8MB payload), which forced the 8x-read XCD-owned build (78us). Atomics are
// device-scope-correct across XCDs (=> executed at a common coherence point, not as
// dirty lines in the requester L2), so writing the bucket with atomicExch should avoid
// the amplification WITHOUT the 8x read: each edge is read exactly once by one XCD.
__global__ __launch_bounds__(256) void build_kernel(const int* __restrict__ esrc,
                                                    const int* __restrict__ edst,
                                                    int* __restrict__ deg,
                                                    int* __restrict__ bucket,
                                                    int* __restrict__ spill,
                                                    int* __restrict__ spill_cnt) {
    for (int i = blockIdx.x * 256 + threadIdx.x; i < NE4; i += gridDim.x * 256) {
        int4 d  = ((const int4*)edst)[i];
        int4 sr = ((const int4*)esrc)[i];
        #pragma unroll
        for (int c = 0; c < 4; ++c) {
            int dd = (c == 0) ? d.x : (c == 1) ? d.y : (c == 2) ? d.z : d.w;
            int ss = (c == 0) ? sr.x : (c == 1) ? sr.y : (c == 2) ? sr.z : sr.w;
            int slot = atomicAdd(&deg[dd], 1);        // device-scope returning atomic
            if (slot < CAP) {
                atomicExch(&bucket[dd * CAP + slot], ss);  // memory-side write: no dirty line
            } else {
                int p = atomicAdd(spill_cnt, 1);
                if (p < SPILL_MAX) { spill[2 * p] = dd; spill[2 * p + 1] = ss; }
            }
        }
    }
}

// ---------------- fp8 e4m3 encode/decode via HW cvt (gfx950) ----------------
__device__ __forceinline__ unsigned char enc_fp8(float f) {
    int w = __builtin_amdgcn_cvt_pk_fp8_f32(f, f, 0, false);
    return (unsigned char)(w & 0xFF);
}

// decode 8 fp8 (one uint2 = lane's feature octet) into 4 packed-f32 accumulators:
// cvt_pk_f32_fp8 yields float2 directly; float2 += float2 -> v_pk_add_f32
// (R14 post-mortem: agg time tracks per-wave VALU issue; pk halves the add count)
__device__ __forceinline__ void acc_fp8v(floatx2 acc[4], uint2 v) {
    acc[0] += __builtin_amdgcn_cvt_pk_f32_fp8((int)v.x, false);
    acc[1] += __builtin_amdgcn_cvt_pk_f32_fp8((int)v.x, true);
    acc[2] += __builtin_amdgcn_cvt_pk_f32_fp8((int)v.y, false);
    acc[3] += __builtin_amdgcn_cvt_pk_f32_fp8((int)v.y, true);
}

__device__ __forceinline__ unsigned packbf2(float lof, float hif) {
    __hip_bfloat16 l = __float2bfloat16(lof), h = __float2bfloat16(hif);
    unsigned short ul, uh;
    __builtin_memcpy(&ul, &l, 2);
    __builtin_memcpy(&uh, &h, 2);
    return ((unsigned)uh << 16) | ul;
}

// ---------------- per-node matmul (separate streaming kernel, R14) ----------------
// MODE 0: t = x[n][f] (f32)
// MODE 1: t = relu(din*S[n][f] + bias[f])   (S = bf16 aggregated row, includes self)
// writes u'[n] = fp8( din * (t_row @ W) )
template <int MODE>
__global__ __launch_bounds__(256) void mm_kernel(const void* __restrict__ in,
                                                 const float* __restrict__ W,
                                                 const float* __restrict__ bias,
                                                 const int* __restrict__ deg,
                                                 unsigned char* __restrict__ uout) {
    __shared__ float Ws[64 * 64];
    __shared__ float hrow[4][64];
    int tid = threadIdx.x;
    {   // stage W (16 KB) via float4
        const float4* Wv = (const float4*)W;
        float4* Wsv = (float4*)Ws;
        #pragma unroll
        for (int i = 0; i < 4; ++i) Wsv[tid + 256 * i] = Wv[tid + 256 * i];
    }
    int local = tid >> 6;            // node within block
    int f = tid & 63;                // feature
    int n = blockIdx.x * 4 + local;  // NN divisible by 4
    float din = rsqrtf((float)(deg[n] + 1));
    float v;
    if (MODE == 0) {
        v = ((const float*)in)[n * 64 + f];
    } else {
        v = __bfloat162float(((const __hip_bfloat16*)in)[n * 64 + f]);
        v = fmaxf(fmaf(din, v, bias[f]), 0.f);
    }
    hrow[local][f] = v;
    __syncthreads();
    float acc = 0.f;
    #pragma unroll
    for (int k = 0; k < 64; ++k)
        acc = fmaf(hrow[local][k], Ws[k * 64 + f], acc);
    uout[n * 64 + f] = enc_fp8(din * acc);
}

// ---------------- pure aggregation core, G=8 over fp8 rows, packed-f32 math ----------------
// wave = 8 edge-groups x 8 lanes; lane covers features [fo*8,fo*8+8) via one dwordx2
// (8B of fp8): per edge, 8 lanes span the 64B row = exactly one cache line. Bucket row
// batch-loaded once (coalesced, predicated) and broadcast by shfl; 4 sweeps fully
// unrolled. Accumulation and merge in float2 (v_pk_add_f32): ~32 fewer VALU inst/wave
// vs scalar (R14: agg time responds to inst count at the marginal issue rate).
// On exit acc[i] = features (fo*8+2i, fo*8+2i+1) of self+neighbor sum, replicated.
__device__ __forceinline__ void agg_row(const int* __restrict__ degv,
                                        const int* __restrict__ bucket,
                                        const uint2* __restrict__ u2,
                                        const int* __restrict__ spill,
                                        const int* __restrict__ spill_cnt,
                                        int n, int lane, int grp, int fo,
                                        floatx2 acc[4]) {
    floatx2 a1[4], a2[4], a3[4];
    #pragma unroll
    for (int i = 0; i < 4; ++i) {
        acc[i] = (floatx2)(0.f); a1[i] = (floatx2)(0.f);
        a2[i] = (floatx2)(0.f);  a3[i] = (floatx2)(0.f);
    }
    int deg = degv[n];
    int dc = deg < CAP ? deg : CAP;
    int cidx = 0;
    if ((lane & 31) < dc) cidx = bucket[n * CAP + (lane & 31)];  // predicated coalesced row load
    if (grp == 0) acc_fp8v(acc, u2[n * 8 + fo]);     // self loop
    int s0 = __shfl(cidx, grp);                      // edges 0..7
    int s1 = __shfl(cidx, grp + 8);                  // edges 8..15
    int s2 = __shfl(cidx, grp + 16);                 // edges 16..23
    int s3 = __shfl(cidx, grp + 24);                 // edges 24..31
    if (grp < dc)      acc_fp8v(acc, u2[s0 * 8 + fo]);
    if (grp + 8 < dc)  acc_fp8v(a1, u2[s1 * 8 + fo]);
    if (grp + 16 < dc) acc_fp8v(a2, u2[s2 * 8 + fo]);
    if (grp + 24 < dc) acc_fp8v(a3, u2[s3 * 8 + fo]);
    if (deg > CAP) {                                 // spill drain: ~never (wave-uniform skip)
        int cnt = *spill_cnt; if (cnt > SPILL_MAX) cnt = SPILL_MAX;
        for (int e = 0; e < cnt; ++e) {
            if (spill[2 * e] == n && grp == 0)
                acc_fp8v(a3, u2[spill[2 * e + 1] * 8 + fo]);
        }
    }
    #pragma unroll
    for (int i = 0; i < 4; ++i)                      // merge sweeps (pk adds)
        acc[i] = (acc[i] + a1[i]) + (a2[i] + a3[i]);
    #pragma unroll
    for (int L = 8; L <= 32; L <<= 1) {              // merge 8 groups: 3 shfl levels
        #pragma unroll
        for (int i = 0; i < 4; ++i) {
            floatx2 t;
            t.x = __shfl_xor(acc[i].x, L);
            t.y = __shfl_xor(acc[i].y, L);
            acc[i] += t;                             // pk add
        }
    }
}

// ---------------- aggregate (POOL=0: S[n][:]=bf16(self+neighbors); POOL=1: gp += din*acc) -----
// one wave per node, 100000 waves: max TLP, no serial nodes (R1/R2 lesson). No W
// staging / no big LDS / no barriers in POOL=0: minimum per-wave issue (R14).
template <int POOL>
__global__ __launch_bounds__(256, 8) void agg_kernel(const int* __restrict__ degv,
                                                     const int* __restrict__ bucket,
                                                     const uint2* __restrict__ uin,
                                                     const int* __restrict__ spill,
                                                     const int* __restrict__ spill_cnt,
                                                     __hip_bfloat16* __restrict__ S,
                                                     float* __restrict__ gp) {
    __shared__ float gpart[64];
    int tid = threadIdx.x;
    if (POOL) {
        if (tid < 64) gpart[tid] = 0.f;
        __syncthreads();
    }
    int lane = tid & 63;
    int grp = lane >> 3;
    int fo = lane & 7;
    int n = blockIdx.x * 4 + (tid >> 6);              // NN divisible by 4
    floatx2 acc[4];
    agg_row(degv, bucket, uin, spill, spill_cnt, n, lane, grp, fo, acc);
    if (POOL) {
        if (grp == 0) {                               // lanes 0..7 hold the full row
            float din = rsqrtf((float)(degv[n] + 1));
            #pragma unroll
            for (int i = 0; i < 4; ++i) {
                atomicAdd(&gpart[fo * 8 + 2 * i],     din * acc[i].x);
                atomicAdd(&gpart[fo * 8 + 2 * i + 1], din * acc[i].y);
            }
        }
        __syncthreads();
        if (tid < 64) atomicAdd(&gp[(blockIdx.x & 63) * 64 + tid], gpart[tid]);
    } else {
        if (grp == 0) {                               // 8 lanes x 16B bf16 = the 128B S row
            uint4 pv;
            pv.x = packbf2(acc[0].x, acc[0].y);
            pv.y = packbf2(acc[1].x, acc[1].y);
            pv.z = packbf2(acc[2].x, acc[2].y);
            pv.w = packbf2(acc[3].x, acc[3].y);
            ((uint4*)S)[n * 8 + fo] = pv;
        }
    }
}

// ---------------- head: g = colsum(gp) + N*b2;  out = g @ Wl + bl ----------------
__global__ __launch_bounds__(64) void head_kernel(const float* __restrict__ gp,
                                                  const float* __restrict__ b2,
                                                  const float* __restrict__ Wl,
                                                  const float* __restrict__ bl,
                                                  float* __restrict__ out) {
    int t = threadIdx.x;  // one wave
    float s = 0.f;
    #pragma unroll 8
    for (int r = 0; r < 64; ++r) s += gp[r * 64 + t];
    float gf = s + (float)NN * b2[t];
    #pragma unroll
    for (int c = 0; c < 10; ++c) {
        float p = gf * Wl[t * 10 + c];
        #pragma unroll
        for (int off = 32; off > 0; off >>= 1) p += __shfl_down(p, off);
        if (t == 0) out[c] = p + bl[c];
    }
}

extern "C" void kernel_launch(void* const* d_in, const int* in_sizes, int n_in,
                              void* d_out, int out_size, void* d_ws, size_t ws_size,
                              hipStream_t stream) {
    const float* x  = (const float*)d_in[0];
    const int* eidx = (const int*)d_in[1];
    const int* esrc = eidx;        // edge_idx[0]
    const int* edst = eidx + NE;   // edge_idx[1]
    const float* W0 = (const float*)d_in[2];
    const float* b0 = (const float*)d_in[3];
    const float* W1 = (const float*)d_in[4];
    const float* b1 = (const float*)d_in[5];
    const float* W2 = (const float*)d_in[6];
    const float* b2 = (const float*)d_in[7];
    const float* Wl = (const float*)d_in[8];
    const float* bl = (const float*)d_in[9];
    float* out = (float*)d_out;

    // workspace layout (4-byte units); ua/ub/S 16B-aligned (even float offsets)
    float* ws = (float*)d_ws;
    size_t off = 0;
    int*   deg    = (int*)(ws + off); off += NN;
    unsigned char* ua = (unsigned char*)(ws + off); off += (size_t)NN * 16;   // fp8 N*64 (6.4MB)
    unsigned char* ub = (unsigned char*)(ws + off); off += (size_t)NN * 16;   // fp8 N*64
    __hip_bfloat16* S = (__hip_bfloat16*)(ws + off); off += (size_t)NN * 32;  // bf16 N*64 (12.8MB)
    float* gp     =        ws + off;  off += 64 * 64;                          // pool partials
    int*   spill_cnt = (int*)(ws + off); off += 4;                             // adjacent to gp: one memset
    int*   spill  = (int*)(ws + off); off += 2 * SPILL_MAX;
    int*   bucket = (int*)(ws + off); off += (size_t)NN * CAP;                 // 12.8 MB

    hipMemsetAsync(deg, 0, NN * sizeof(int), stream);
    hipMemsetAsync(gp, 0, (64 * 64 + 4) * sizeof(float), stream);  // gp + spill_cnt

    // single-pass atomic bucket build (each edge read ONCE; R14 atomics-are-memory-side probe)
    build_kernel<<<2048, 256, 0, stream>>>(esrc, edst, deg, bucket, spill, spill_cnt);

    // layer 0 matmul: ua = fp8(din*(x@W0))
    mm_kernel<0><<<NN / 4, 256, 0, stream>>>(x, W0, nullptr, deg, ua);
    // S = self+neighbor sum of ua (pure gather kernel)
    agg_kernel<0><<<NN / 4, 256, 0, stream>>>(deg, bucket, (const uint2*)ua, spill, spill_cnt, S, gp);
    // layer 1 matmul: ub = fp8(din*(relu(din*S+b0)@W1))
    mm_kernel<1><<<NN / 4, 256, 0, stream>>>(S, W1, b0, deg, ub);
    // S = self+neighbor sum of ub
    agg_kernel<0><<<NN / 4, 256, 0, stream>>>(deg, bucket, (const uint2*)ub, spill, spill_cnt, S, gp);
    // layer 2 matmul: ua = fp8(din*(relu(din*S+b1)@W2))
    mm_kernel<1><<<NN / 4, 256, 0, stream>>>(S, W2, b1, deg, ua);
    // final aggregate + global pool (din folded; N*b2 added in head)
    agg_kernel<1><<<NN / 4, 256, 0, stream>>>(deg, bucket, (const uint2*)ua, spill, spill_cnt, S, gp);
    head_kernel<<<1, 64, 0, stream>>>(gp, b2, Wl, bl, out);
}

// Round 16
// 332.556 us; speedup vs baseline: 1.1985x; 1.1985x over previous
//
#include <hip/hip_runtime.h>
#include <hip/hip_bf16.h>

#define NN 100000
#define NE 1200000
#define NE4 (NE / 4)                         // 300000
#define XCD_N 8
#define NPX (NN / XCD_N)                     // 12500 nodes per XCD
#define CAP 64                               // bucket capacity (P(deg>64) ~ 15 sigma)
#define SPILL_MAX 4096

typedef float floatx2 __attribute__((ext_vector_type(2)));

// ---------------- single-pass CSR-bucket build, XCD-partitioned (R6-proven) ----------------
// block b (XCD = b&7, normal dispatch only -- R5: coop launch breaks this mapping)
// stripes the full edge list with its XCD's sibling blocks and handles only dsts
// in its 12500-node range: deg/bucket lines are written by exactly one XCD ->
// L2-local atomics, dirty lines evict once. The 8x edge-list re-read is the proven
// cheapest correct scatter: R3/R15 both measured ~16x HBM write amplification for
// any non-owned store/atomic (75-85MB writes for 4.8MB payload); R10/R13 two-phase
// partitions measured equal-or-worse (111 / ~78us).
__global__ __launch_bounds__(256) void bucket_fill_kernel(const int* __restrict__ esrc,
                                                          const int* __restrict__ edst,
                                                          int* __restrict__ deg,
                                                          int* __restrict__ bucket,
                                                          int* __restrict__ spill,
                                                          int* __restrict__ spill_cnt) {
    int xcd = blockIdx.x & 7;
    int sub = blockIdx.x >> 3;
    int nsub = gridDim.x >> 3;
    int lo = xcd * NPX;
    for (int i = sub * 256 + threadIdx.x; i < NE4; i += nsub * 256) {
        int4 d  = ((const int4*)edst)[i];
        int4 sr = ((const int4*)esrc)[i];
        #pragma unroll
        for (int c = 0; c < 4; ++c) {
            int dd = (c == 0) ? d.x : (c == 1) ? d.y : (c == 2) ? d.z : d.w;
            int ss = (c == 0) ? sr.x : (c == 1) ? sr.y : (c == 2) ? sr.z : sr.w;
            if ((unsigned)(dd - lo) < NPX) {
                int slot = atomicAdd(&deg[dd], 1);
                if (slot < CAP) {
                    bucket[dd * CAP + slot] = ss;
                } else {
                    int p = atomicAdd(spill_cnt, 1);
                    if (p < SPILL_MAX) { spill[2 * p] = dd; spill[2 * p + 1] = ss; }
                }
            }
        }
    }
}

// ---------------- fp8 e4m3 encode/decode via HW cvt (gfx950) ----------------
__device__ __forceinline__ unsigned char enc_fp8(float f) {
    int w = __builtin_amdgcn_cvt_pk_fp8_f32(f, f, 0, false);
    return (unsigned char)(w & 0xFF);
}

// decode 8 fp8 (one uint2 = 8 bytes = lane's feature octet) and accumulate
__device__ __forceinline__ void acc_fp8(float acc[8], uint2 v) {
    floatx2 a0 = __builtin_amdgcn_cvt_pk_f32_fp8((int)v.x, false);
    floatx2 a1 = __builtin_amdgcn_cvt_pk_f32_fp8((int)v.x, true);
    floatx2 a2 = __builtin_amdgcn_cvt_pk_f32_fp8((int)v.y, false);
    floatx2 a3 = __builtin_amdgcn_cvt_pk_f32_fp8((int)v.y, true);
    acc[0] += a0.x; acc[1] += a0.y;
    acc[2] += a1.x; acc[3] += a1.y;
    acc[4] += a2.x; acc[5] += a2.y;
    acc[6] += a3.x; acc[7] += a3.y;
}

// ---------------- layer-0 matmul: u8 = fp8(din * (x @ W0)) ----------------
__global__ __launch_bounds__(256) void mm0_kernel(const float* __restrict__ in,
                                                  const float* __restrict__ W,
                                                  const int* __restrict__ deg,
                                                  unsigned char* __restrict__ u8) {
    __shared__ float Ws[64 * 64];
    __shared__ float hrow[4][64];
    int tid = threadIdx.x;
    {   // stage W (16 KB) via float4
        const float4* Wv = (const float4*)W;
        float4* Wsv = (float4*)Ws;
        #pragma unroll
        for (int i = 0; i < 4; ++i) Wsv[tid + 256 * i] = Wv[tid + 256 * i];
    }
    int local = tid >> 6;            // node within block
    int f = tid & 63;                // feature
    int n = blockIdx.x * 4 + local;  // NN divisible by 4
    float din = rsqrtf((float)(deg[n] + 1));
    hrow[local][f] = in[n * 64 + f];
    __syncthreads();
    float acc = 0.f;
    #pragma unroll
    for (int k = 0; k < 64; ++k)
        acc = fmaf(hrow[local][k], Ws[k * 64 + f], acc);
    u8[n * 64 + f] = enc_fp8(din * acc);
}

// ---------------- aggregation core, G=8 over fp8 rows ----------------
// wave = 8 edge-groups x 8 lanes; lane covers features [fo*8,fo*8+8) via one
// dwordx2 (8B of fp8): per edge, 8 lanes span the 64B row = exactly one cache
// line. Bucket row batch-loaded once (coalesced, predicated) and broadcast by
// shfl. On exit acc[0..8) = aggregated row (self + neighbors), replicated
// across the 8 groups. 15-round result: this phase is invariant at ~67-86us
// under bytes/requests/MLP/occupancy/chain-depth variation -- only per-wave
// instruction count moves it (R14: ~16 inst/us marginal).
__device__ __forceinline__ void agg_row(const int* __restrict__ degv,
                                        const int* __restrict__ bucket,
                                        const uint2* __restrict__ u2,
                                        const int* __restrict__ spill,
                                        const int* __restrict__ spill_cnt,
                                        int n, int lane, int grp, int fo,
                                        float acc[8]) {
    float acc2[8];
    #pragma unroll
    for (int i = 0; i < 8; ++i) { acc[i] = 0.f; acc2[i] = 0.f; }
    int deg = degv[n];
    int dc = deg < CAP ? deg : CAP;
    int cidx = -1;
    if (lane < dc) cidx = bucket[n * CAP + lane];    // one coalesced row load
    if (grp == 0) acc_fp8(acc, u2[n * 8 + fo]);      // self loop
    int s0 = __shfl(cidx, grp);                      // sweep 0: edges 0..7
    int s1 = __shfl(cidx, grp + 8);                  // sweep 1: edges 8..15
    if (grp < dc) acc_fp8(acc, u2[s0 * 8 + fo]);
    if (grp + 8 < dc) acc_fp8(acc2, u2[s1 * 8 + fo]);
    for (int j = grp + 16; j < dc; j += 8) {         // deg in (16,64]
        int s = __shfl(cidx, j);
        acc_fp8(acc, u2[s * 8 + fo]);
    }
    if (deg > CAP) {                                 // spill drain: ~never taken
        int cnt = *spill_cnt; if (cnt > SPILL_MAX) cnt = SPILL_MAX;
        for (int e = 0; e < cnt; ++e) {
            if (spill[2 * e] == n && grp == 0)
                acc_fp8(acc2, u2[spill[2 * e + 1] * 8 + fo]);
        }
    }
    #pragma unroll
    for (int i = 0; i < 8; ++i) {                    // merge sweeps + 8 groups
        float v = acc[i] + acc2[i];
        v += __shfl_xor(v, 8);
        v += __shfl_xor(v, 16);
        v += __shfl_xor(v, 32);
        acc[i] = v;
    }
}

// ---------------- fused aggregate + finalize + next-layer matmul (best measured: R11) --------
// per node n (one wave, 100000 waves -- R1/R2 lesson: never serialize nodes):
//   acc = u[n] + sum_{src} u[src]; t = relu(din*acc + bias); uout = fp8(din*(t@W))
// Fused beats split (R14): the S round-trip + extra dispatches cost more than the
// ~250-inst epilogue does (85.5 vs 70+13+overhead per layer).
__global__ __launch_bounds__(256, 6) void aggmm_kernel(const int* __restrict__ degv,
                                                       const int* __restrict__ bucket,
                                                       const uint2* __restrict__ uin,
                                                       const int* __restrict__ spill,
                                                       const int* __restrict__ spill_cnt,
                                                       const float* __restrict__ bias,
                                                       const float* __restrict__ W,
                                                       unsigned char* __restrict__ uout) {
    __shared__ float Ws[64 * 64];
    __shared__ float hrow[4][64];
    int tid = threadIdx.x;
    {   // stage W (16 KB) via float4
        const float4* Wv = (const float4*)W;
        float4* Wsv = (float4*)Ws;
        #pragma unroll
        for (int i = 0; i < 4; ++i) Wsv[tid + 256 * i] = Wv[tid + 256 * i];
    }
    __syncthreads();
    int wid = tid >> 6;
    int lane = tid & 63;
    int grp = lane >> 3;
    int fo = lane & 7;
    int n = blockIdx.x * 4 + wid;                     // NN divisible by 4
    float acc[8];
    agg_row(degv, bucket, uin, spill, spill_cnt, n, lane, grp, fo, acc);
    float din = rsqrtf((float)(degv[n] + 1));
    if (grp == 0) {                                   // lanes 0..7 hold the full row
        float4 blo = ((const float4*)bias)[fo * 2];
        float4 bhi = ((const float4*)bias)[fo * 2 + 1];
        float4 lo, hi;
        lo.x = fmaxf(fmaf(din, acc[0], blo.x), 0.f);
        lo.y = fmaxf(fmaf(din, acc[1], blo.y), 0.f);
        lo.z = fmaxf(fmaf(din, acc[2], blo.z), 0.f);
        lo.w = fmaxf(fmaf(din, acc[3], blo.w), 0.f);
        hi.x = fmaxf(fmaf(din, acc[4], bhi.x), 0.f);
        hi.y = fmaxf(fmaf(din, acc[5], bhi.y), 0.f);
        hi.z = fmaxf(fmaf(din, acc[6], bhi.z), 0.f);
        hi.w = fmaxf(fmaf(din, acc[7], bhi.w), 0.f);
        ((float4*)hrow[wid])[fo * 2] = lo;            // t row -> per-wave LDS
        ((float4*)hrow[wid])[fo * 2 + 1] = hi;
    }
    // same-wave LDS RAW (write above, read below): in-order LDS + compiler
    // lgkmcnt ordering through the shared array; no barrier needed (R7-proven).
    float o = 0.f;
    const float4* hv = (const float4*)hrow[wid];
    #pragma unroll
    for (int k4 = 0; k4 < 16; ++k4) {
        float4 h = hv[k4];                            // broadcast read (all lanes same addr)
        int kb = k4 * 4;
        o = fmaf(h.x, Ws[(kb + 0) * 64 + lane], o);
        o = fmaf(h.y, Ws[(kb + 1) * 64 + lane], o);
        o = fmaf(h.z, Ws[(kb + 2) * 64 + lane], o);
        o = fmaf(h.w, Ws[(kb + 3) * 64 + lane], o);
    }
    uout[n * 64 + lane] = enc_fp8(din * o);
}

// ---------------- final aggregate + global pool: gp += din*agg ----------------
__global__ __launch_bounds__(256, 6) void aggpool_kernel(const int* __restrict__ degv,
                                                         const int* __restrict__ bucket,
                                                         const uint2* __restrict__ uin,
                                                         const int* __restrict__ spill,
                                                         const int* __restrict__ spill_cnt,
                                                         float* __restrict__ gp) {
    __shared__ float gpart[64];
    int tid = threadIdx.x;
    if (tid < 64) gpart[tid] = 0.f;
    __syncthreads();
    int lane = tid & 63;
    int grp = lane >> 3;
    int fo = lane & 7;
    int n = blockIdx.x * 4 + (tid >> 6);              // NN divisible by 4
    float acc[8];
    agg_row(degv, bucket, uin, spill, spill_cnt, n, lane, grp, fo, acc);
    if (grp == 0) {                                   // lanes 0..7 hold the full row
        float din = rsqrtf((float)(degv[n] + 1));
        #pragma unroll
        for (int i = 0; i < 8; ++i) atomicAdd(&gpart[fo * 8 + i], din * acc[i]);
    }
    __syncthreads();
    if (tid < 64) atomicAdd(&gp[(blockIdx.x & 63) * 64 + tid], gpart[tid]);
}

// ---------------- head: g = colsum(gp) + N*b2;  out = g @ Wl + bl ----------------
__global__ __launch_bounds__(64) void head_kernel(const float* __restrict__ gp,
                                                  const float* __restrict__ b2,
                                                  const float* __restrict__ Wl,
                                                  const float* __restrict__ bl,
                                                  float* __restrict__ out) {
    int t = threadIdx.x;  // one wave
    float s = 0.f;
    #pragma unroll 8
    for (int r = 0; r < 64; ++r) s += gp[r * 64 + t];
    float gf = s + (float)NN * b2[t];
    #pragma unroll
    for (int c = 0; c < 10; ++c) {
        float p = gf * Wl[t * 10 + c];
        #pragma unroll
        for (int off = 32; off > 0; off >>= 1) p += __shfl_down(p, off);
        if (t == 0) out[c] = p + bl[c];
    }
}

extern "C" void kernel_launch(void* const* d_in, const int* in_sizes, int n_in,
                              void* d_out, int out_size, void* d_ws, size_t ws_size,
                              hipStream_t stream) {
    const float* x  = (const float*)d_in[0];
    const int* eidx = (const int*)d_in[1];
    const int* esrc = eidx;        // edge_idx[0]
    const int* edst = eidx + NE;   // edge_idx[1]
    const float* W0 = (const float*)d_in[2];
    const float* b0 = (const float*)d_in[3];
    const float* W1 = (const float*)d_in[4];
    const float* b1 = (const float*)d_in[5];
    const float* W2 = (const float*)d_in[6];
    const float* b2 = (const float*)d_in[7];
    const float* Wl = (const float*)d_in[8];
    const float* bl = (const float*)d_in[9];
    float* out = (float*)d_out;

    // workspace layout (4-byte units); ua/ub 8B-aligned for uint2 gathers
    float* ws = (float*)d_ws;
    size_t off = 0;
    int*   deg    = (int*)(ws + off); off += NN;
    unsigned char* ua = (unsigned char*)(ws + off); off += (size_t)NN * 16;   // fp8 N*64 (6.4MB)
    unsigned char* ub = (unsigned char*)(ws + off); off += (size_t)NN * 16;   // fp8 N*64
    float* gp     =        ws + off;  off += 64 * 64;                          // pool partials
    int*   spill_cnt = (int*)(ws + off); off += 4;                             // adjacent to gp: one memset
    int*   spill  = (int*)(ws + off); off += 2 * SPILL_MAX;
    int*   bucket = (int*)(ws + off); off += (size_t)NN * CAP;                 // 25.6 MB

    hipMemsetAsync(deg, 0, NN * sizeof(int), stream);
    hipMemsetAsync(gp, 0, (64 * 64 + 4) * sizeof(float), stream);  // gp + spill_cnt

    // single-pass bucket CSR build (normal dispatch: R5 proved coop launch breaks b&7->XCD)
    bucket_fill_kernel<<<2048, 256, 0, stream>>>(esrc, edst, deg, bucket, spill, spill_cnt);

    // layer 0 matmul: ua = fp8(din*(x@W0))
    mm0_kernel<<<NN / 4, 256, 0, stream>>>(x, W0, deg, ua);
    // fused: agg(ua) + relu/bias(b0) + matmul(W1) -> ub
    aggmm_kernel<<<NN / 4, 256, 0, stream>>>(deg, bucket, (const uint2*)ua, spill, spill_cnt, b0, W1, ub);
    // fused: agg(ub) + relu/bias(b1) + matmul(W2) -> ua
    aggmm_kernel<<<NN / 4, 256, 0, stream>>>(deg, bucket, (const uint2*)ub, spill, spill_cnt, b1, W2, ua);
    // fused: agg(ua) + global pool (din folded; N*b2 added in head)
    aggpool_kernel<<<NN / 4, 256, 0, stream>>>(deg, bucket, (const uint2*)ua, spill, spill_cnt, gp);
    head_kernel<<<1, 64, 0, stream>>>(gp, b2, Wl, bl, out);
}